// Round 1
// baseline (1287.117 us; speedup 1.0000x reference)
//
#include <hip/hip_runtime.h>
#include <math.h>

#define MB 64     // pixels per block (M tile)
#define NB 64     // output channels per block (N tile)
#define KD 129    // contraction dim: 2*MAX_FREQ+1

// 256 threads: phase 1 computes Y[k][p] into LDS (4 waves split the m-chain),
// phase 2 is a 4x4-register-tiled fp32 GEMM out[p,h] = sum_k Y[p,k] W[h,k] + b[h].
__global__ __launch_bounds__(256, 2)
void sph_fused(const float* __restrict__ x, const float* __restrict__ W,
               const float* __restrict__ b, float* __restrict__ out) {
    __shared__ float Yt[KD * MB];   // [k][p], k-major, stride 64
    __shared__ float Ws[KD * NB];   // [k][h], k-major, stride 64

    const int tid = threadIdx.x;
    const int p0 = blockIdx.x * MB;
    const int h0 = blockIdx.y * NB;

    // ---- stage W transposed into LDS: Ws[k][hh] = W[(h0+hh)*129 + k] ----
    {
        const int hh = tid >> 2;     // 0..63
        const int kp = tid & 3;      // 0..3
        #pragma unroll
        for (int i = 0; i < 33; ++i) {
            int k = kp + 4 * i;
            if (k < KD) Ws[k * NB + hh] = W[(h0 + hh) * KD + k];
        }
    }

    // ---- phase 1: spherical harmonics Y into LDS ----
    {
        const int pix = tid & 63;    // pixel within tile
        const int s   = tid >> 6;    // wave id 0..3 -> m range [16s+1, 16s+16]
        const int m0  = 16 * s;
        const int gp  = p0 + pix;
        const float2 tp = *(const float2*)&x[gp * 2];
        const float theta = tp.x, phi = tp.y;

        const float ct = cosf(phi);
        const float st = sqrtf(fmaxf(1.0f - ct * ct, 0.0f));

        // Pbar_{m0}^{m0} = sqrt(1/4pi) * [prod_{i=1..m0} sqrt((2i+1)/(2i))] * st^m0
        // (sign (+1): m0 is even)
        float prod = 1.0f;
        for (int i = 1; i <= m0; ++i) prod *= (2.0f * i + 1.0f) / (2.0f * i);
        const float K0 = sqrtf(prod);
        const float s2 = st * st, s4 = s2 * s2, s8 = s4 * s4, s16 = s8 * s8;
        float stp = 1.0f;
        for (int i = 0; i < s; ++i) stp *= s16;   // st^(16s)
        float pm = 0.28209479177387814f * K0 * stp;  // sqrt(1/(4pi)) * ...

        // rotation state: cos(m0*theta), sin(m0*theta); step rotation by theta
        float cm, sm, c1, s1;
        sincosf((float)m0 * theta, &sm, &cm);
        sincosf(theta, &s1, &c1);

        if (s == 0) {
            // m = 0: ybar = sqrt(3) * ct * Pbar_0^0
            Yt[64 * MB + pix] = 1.7320508075688772f * ct * pm;
        }

        #pragma unroll
        for (int m = m0 + 1; m <= m0 + 16; ++m) {
            // Pbar_m^m = -sqrt((2m+1)/(2m)) * st * Pbar_{m-1}^{m-1}
            pm *= -sqrtf((2.0f * m + 1.0f) / (2.0f * m)) * st;
            // rotate (cm, sm) -> cos(m*theta), sin(m*theta)
            const float cn = cm * c1 - sm * s1;
            const float sn = sm * c1 + cm * s1;
            cm = cn; sm = sn;
            // climb l = m -> m+1: a = sqrt(2m+3)
            const float yb = sqrtf(2.0f * m + 3.0f) * ct * pm;
            const float t = (m & 1) ? -1.4142135623730951f : 1.4142135623730951f;
            Yt[(64 + m) * MB + pix] = t * yb * cm;   // pos branch: cos(m theta)
            Yt[(64 - m) * MB + pix] = t * yb * sm;   // neg branch: sin(m theta)
        }
    }
    __syncthreads();

    // ---- phase 2: 4x4 register-tiled GEMM ----
    const int tx = tid & 15;   // h quad
    const int ty = tid >> 4;   // p quad
    const float4 bb = *(const float4*)&b[h0 + tx * 4];

    float acc[4][4];
    #pragma unroll
    for (int i = 0; i < 4; ++i) {
        acc[i][0] = bb.x; acc[i][1] = bb.y; acc[i][2] = bb.z; acc[i][3] = bb.w;
    }

    #pragma unroll 3
    for (int k = 0; k < KD; ++k) {
        const float4 y = *(const float4*)&Yt[k * MB + ty * 4];
        const float4 w = *(const float4*)&Ws[k * NB + tx * 4];
        acc[0][0] = fmaf(y.x, w.x, acc[0][0]);
        acc[0][1] = fmaf(y.x, w.y, acc[0][1]);
        acc[0][2] = fmaf(y.x, w.z, acc[0][2]);
        acc[0][3] = fmaf(y.x, w.w, acc[0][3]);
        acc[1][0] = fmaf(y.y, w.x, acc[1][0]);
        acc[1][1] = fmaf(y.y, w.y, acc[1][1]);
        acc[1][2] = fmaf(y.y, w.z, acc[1][2]);
        acc[1][3] = fmaf(y.y, w.w, acc[1][3]);
        acc[2][0] = fmaf(y.z, w.x, acc[2][0]);
        acc[2][1] = fmaf(y.z, w.y, acc[2][1]);
        acc[2][2] = fmaf(y.z, w.z, acc[2][2]);
        acc[2][3] = fmaf(y.z, w.w, acc[2][3]);
        acc[3][0] = fmaf(y.w, w.x, acc[3][0]);
        acc[3][1] = fmaf(y.w, w.y, acc[3][1]);
        acc[3][2] = fmaf(y.w, w.z, acc[3][2]);
        acc[3][3] = fmaf(y.w, w.w, acc[3][3]);
    }

    // ---- epilogue: coalesced float4 stores ----
    #pragma unroll
    for (int i = 0; i < 4; ++i) {
        const size_t p = (size_t)(p0 + ty * 4 + i);
        float4 o;
        o.x = acc[i][0]; o.y = acc[i][1]; o.z = acc[i][2]; o.w = acc[i][3];
        *(float4*)&out[p * 1024 + h0 + tx * 4] = o;
    }
}

extern "C" void kernel_launch(void* const* d_in, const int* in_sizes, int n_in,
                              void* d_out, int out_size, void* d_ws, size_t ws_size,
                              hipStream_t stream) {
    const float* x = (const float*)d_in[0];   // (4,128,256,1,2)
    const float* W = (const float*)d_in[1];   // (1024,129)
    const float* b = (const float*)d_in[2];   // (1024,)
    float* out = (float*)d_out;               // (4,128,256,1,1024)

    const int P = in_sizes[0] / 2;            // 131072 pixels
    dim3 grid(P / MB, 1024 / NB);
    sph_fused<<<grid, dim3(256), 0, stream>>>(x, W, b, out);
}

// Round 2
// 1002.882 us; speedup vs baseline: 1.2834x; 1.2834x over previous
//
#include <hip/hip_runtime.h>
#include <math.h>

#define KP 136   // padded K stride in LDS (elements); 136*2B row stride -> 2-way banks only

typedef short v8s __attribute__((ext_vector_type(8)));
typedef float v4f __attribute__((ext_vector_type(4)));

// round-to-nearest-even float -> bf16 bits; also returns the bf16 value as float
__device__ __forceinline__ unsigned short bf16_rne(float f, float* back) {
    union { float f; unsigned u; } a; a.f = f;
    unsigned r = a.u + 0x7FFFu + ((a.u >> 16) & 1u);
    unsigned short h = (unsigned short)(r >> 16);
    union { unsigned u; float f; } bb; bb.u = (unsigned)h << 16;
    *back = bb.f;
    return h;
}

// Fused: phase1 computes Y[128 pixels][129] (split bf16 hi/lo) into LDS,
// W tile 128x129 staged split into LDS, then 3-product split-bf16 MFMA GEMM.
__global__ __launch_bounds__(512, 2)
void sph_mfma(const float* __restrict__ x, const float* __restrict__ W,
              const float* __restrict__ bias, float* __restrict__ out) {
    __shared__ alignas(16) unsigned short Yhi[128 * KP];
    __shared__ alignas(16) unsigned short Ylo[128 * KP];
    __shared__ alignas(16) unsigned short Whi[128 * KP];
    __shared__ alignas(16) unsigned short Wlo[128 * KP];
    __shared__ float y128[128];   // Y[:,k=128] column, exact fp32
    __shared__ float w128[128];   // W[:,k=128] column, exact fp32

    const int tid = threadIdx.x;
    const int p0 = blockIdx.x * 128;   // pixel tile origin
    const int h0 = blockIdx.y * 128;   // channel tile origin

    // ---- stage W tile: Whi/Wlo[h][k], k<128; k==128 -> w128 (fp32) ----
    {
        const int r  = tid >> 2;        // 0..127 (row within tile)
        const int cp = tid & 3;
        const float* wrow = W + (size_t)(h0 + r) * 129;
        #pragma unroll
        for (int i = 0; i < 33; ++i) {
            const int k = cp + 4 * i;
            if (k < 128) {
                const float w = wrow[k];
                float hf;
                Whi[r * KP + k] = bf16_rne(w, &hf);
                float dummy;
                Wlo[r * KP + k] = bf16_rne(w - hf, &dummy);
            } else if (k == 128) {
                w128[r] = wrow[128];
            }
        }
    }

    // ---- phase 1: spherical harmonics Y into LDS (4 m-segments per pixel) ----
    {
        const int pix = tid & 127;      // pixel within tile
        const int s   = tid >> 7;       // segment 0..3 -> m in [16s+1, 16s+16]
        const int m0  = 16 * s;
        const float2 tp = *(const float2*)&x[(size_t)(p0 + pix) * 2];
        const float theta = tp.x, phi = tp.y;

        const float ct = cosf(phi);
        const float st = sqrtf(fmaxf(1.0f - ct * ct, 0.0f));

        // jump-start Pbar_{m0}^{m0} = sqrt(1/4pi) * sqrt(prod (2i+1)/(2i)) * st^m0  (m0 even -> +)
        float prod = 1.0f;
        for (int i = 1; i <= m0; ++i) prod *= (2.0f * i + 1.0f) / (2.0f * i);
        const float s2 = st * st, s4 = s2 * s2, s8 = s4 * s4, s16 = s8 * s8;
        float stp = 1.0f;
        for (int i = 0; i < s; ++i) stp *= s16;
        float pm = 0.28209479177387814f * sqrtf(prod) * stp;

        float cm, sm, c1, s1;
        sincosf((float)m0 * theta, &sm, &cm);
        sincosf(theta, &s1, &c1);

        if (s == 0) {
            const float y0 = 1.7320508075688772f * ct * pm;   // k = 64
            float hf, d;
            Yhi[pix * KP + 64] = bf16_rne(y0, &hf);
            Ylo[pix * KP + 64] = bf16_rne(y0 - hf, &d);
        }

        #pragma unroll
        for (int j = 1; j <= 16; ++j) {
            const int m = m0 + j;
            pm *= -sqrtf((2.0f * m + 1.0f) / (2.0f * m)) * st;
            const float cn = cm * c1 - sm * s1;
            const float sn = sm * c1 + cm * s1;
            cm = cn; sm = sn;
            const float yb = sqrtf(2.0f * m + 3.0f) * ct * pm;
            const float t  = (m & 1) ? -1.4142135623730951f : 1.4142135623730951f;
            const float vp = t * yb * cm;   // k = 64 + m
            const float vn = t * yb * sm;   // k = 64 - m
            {
                float hf, d;
                const int kn = 64 - m;
                Yhi[pix * KP + kn] = bf16_rne(vn, &hf);
                Ylo[pix * KP + kn] = bf16_rne(vn - hf, &d);
            }
            const int kp = 64 + m;
            if (kp < 128) {
                float hf, d;
                Yhi[pix * KP + kp] = bf16_rne(vp, &hf);
                Ylo[pix * KP + kp] = bf16_rne(vp - hf, &d);
            } else {
                y128[pix] = vp;             // m == 64
            }
        }
    }
    __syncthreads();

    // ---- phase 2: split-bf16 MFMA GEMM, k = 0..127 in 4 steps of 32 ----
    const int lane = tid & 63;
    const int wid  = tid >> 6;          // 0..7
    const int wm   = wid & 1;           // 2 wave-rows  -> 64 pixels each
    const int wn   = wid >> 1;          // 4 wave-cols  -> 32 channels each
    const int l16  = lane & 15;
    const int quad = lane >> 4;

    const int arow0 = wm * 64 + l16;    // + mt*16
    const int brow0 = wn * 32 + l16;    // + tn*16

    v4f acc[4][2];
    #pragma unroll
    for (int mt = 0; mt < 4; ++mt)
        #pragma unroll
        for (int tn = 0; tn < 2; ++tn)
            acc[mt][tn] = (v4f){0.f, 0.f, 0.f, 0.f};

    #pragma unroll
    for (int ks = 0; ks < 4; ++ks) {
        const int ko = ks * 32 + quad * 8;
        v8s ah[4], al[4], bh[2], bl[2];
        #pragma unroll
        for (int mt = 0; mt < 4; ++mt) {
            ah[mt] = *(const v8s*)&Yhi[(arow0 + mt * 16) * KP + ko];
            al[mt] = *(const v8s*)&Ylo[(arow0 + mt * 16) * KP + ko];
        }
        #pragma unroll
        for (int tn = 0; tn < 2; ++tn) {
            bh[tn] = *(const v8s*)&Whi[(brow0 + tn * 16) * KP + ko];
            bl[tn] = *(const v8s*)&Wlo[(brow0 + tn * 16) * KP + ko];
        }
        #pragma unroll
        for (int mt = 0; mt < 4; ++mt)
            #pragma unroll
            for (int tn = 0; tn < 2; ++tn) {
                acc[mt][tn] = __builtin_amdgcn_mfma_f32_16x16x32_bf16(ah[mt], bh[tn], acc[mt][tn], 0, 0, 0);
                acc[mt][tn] = __builtin_amdgcn_mfma_f32_16x16x32_bf16(ah[mt], bl[tn], acc[mt][tn], 0, 0, 0);
                acc[mt][tn] = __builtin_amdgcn_mfma_f32_16x16x32_bf16(al[mt], bh[tn], acc[mt][tn], 0, 0, 0);
            }
    }

    // ---- epilogue: + bias + exact rank-1 update for k=128, fp32 stores ----
    #pragma unroll
    for (int tn = 0; tn < 2; ++tn) {
        const int hc = wn * 32 + tn * 16 + l16;       // channel within tile
        const float bv = bias[h0 + hc];
        const float wv = w128[hc];
        #pragma unroll
        for (int mt = 0; mt < 4; ++mt) {
            #pragma unroll
            for (int i = 0; i < 4; ++i) {
                const int row = wm * 64 + mt * 16 + quad * 4 + i;   // pixel within tile
                const float o = acc[mt][tn][i] + bv + y128[row] * wv;
                out[(size_t)(p0 + row) * 1024 + (h0 + hc)] = o;
            }
        }
    }
}

extern "C" void kernel_launch(void* const* d_in, const int* in_sizes, int n_in,
                              void* d_out, int out_size, void* d_ws, size_t ws_size,
                              hipStream_t stream) {
    const float* x = (const float*)d_in[0];   // (4,128,256,1,2) -> 131072 pixels
    const float* W = (const float*)d_in[1];   // (1024,129)
    const float* b = (const float*)d_in[2];   // (1024,)
    float* out = (float*)d_out;               // (131072,1024)

    const int P = in_sizes[0] / 2;
    dim3 grid(P / 128, 1024 / 128);
    sph_mfma<<<grid, dim3(512), 0, stream>>>(x, W, b, out);
}